// Round 9
// baseline (553.736 us; speedup 1.0000x reference)
//
#include <hip/hip_runtime.h>
#include <math.h>

typedef unsigned short u16;
typedef unsigned int   u32;
typedef unsigned long long u64;
typedef __attribute__((ext_vector_type(4))) float f32x4;
typedef __attribute__((ext_vector_type(4))) unsigned int u32x4;
typedef __attribute__((ext_vector_type(8))) _Float16 f16x8;
typedef __attribute__((ext_vector_type(8))) short s16x8;   // 8 bf16

#define NROWS   32768
#define CDIM    512
#define TDIM    768
#define KKEY    128
#define FFDIM   2048
#define NB      8
#define RPB     4096
#define LN_EPS_ 1e-5f
#define TINV    (1.0f/0.07f)
#define RESCUE_MARGIN 1e-5f

__device__ __forceinline__ u16 f2h(float f){ _Float16 h=(_Float16)f; return __builtin_bit_cast(u16,h); }
__device__ __forceinline__ float h2f(u16 v){ return (float)__builtin_bit_cast(_Float16, v); }
__device__ __forceinline__ unsigned pk2(float a,float b){ return (unsigned)f2h(a)|((unsigned)f2h(b)<<16); }
__device__ __forceinline__ u16 f2b(float f){
  u32 u = __builtin_bit_cast(u32, f);
  u32 r = (u + 0x7fffu + ((u>>16)&1u)) >> 16;
  return (u16)r;
}
__device__ __forceinline__ float b2f(u16 h){ u32 u = ((u32)h)<<16; return __builtin_bit_cast(float, u); }
__device__ __forceinline__ unsigned pkb(float a,float b){ return (unsigned)f2b(a)|((unsigned)f2b(b)<<16); }

__device__ __forceinline__ void gl_lds16(const void* g, void* l){
  __builtin_amdgcn_global_load_lds(
      (const __attribute__((address_space(1))) u32*)g,
      (__attribute__((address_space(3))) u32*)l, 16, 0, 0);
}

__device__ __forceinline__ float fast_exp2(float x){
#if __has_builtin(__builtin_amdgcn_exp2f)
  return __builtin_amdgcn_exp2f(x);
#else
  return exp2f(x);
#endif
}
__device__ __forceinline__ float fast_rcp(float x){
#if __has_builtin(__builtin_amdgcn_rcpf)
  return __builtin_amdgcn_rcpf(x);
#else
  return 1.0f/x;
#endif
}

__device__ __forceinline__ float wsumf(float v){
#pragma unroll
  for(int o=1;o<64;o<<=1) v+=__shfl_xor(v,o);
  return v; }
__device__ __forceinline__ float wmaxf(float v){
#pragma unroll
  for(int o=1;o<64;o<<=1) v=fmaxf(v,__shfl_xor(v,o));
  return v; }
__device__ __forceinline__ double wsumd(double v){
#pragma unroll
  for(int o=1;o<64;o<<=1) v+=__shfl_xor(v,o);
  return v; }
__device__ __forceinline__ double wmaxd(double v){
#pragma unroll
  for(int o=1;o<64;o<<=1){ double t=__shfl_xor(v,o); v = t>v ? t : v; }
  return v; }

__device__ __forceinline__ double blocksumd4(double v, double* red){
  const int lane = threadIdx.x & 63, w = threadIdx.x >> 6;
  v = wsumd(v);
  __syncthreads();
  if (lane==0) red[w] = v;
  __syncthreads();
  return red[0]+red[1]+red[2]+red[3];
}

// ---------------------------------------------------------------------------
// Unified weight transpose+cast. MODE: 0=f32, 1=f16, 2=bf16
// ---------------------------------------------------------------------------
template<int R, int C, int MODE>
__device__ __forceinline__ void tr_tile(const float* __restrict__ in, void* __restrict__ out,
                                        int bx, int by, float (*tile)[33])
{
  int c0 = bx*32, r0 = by*32;
  int tx = threadIdx.x, ty = threadIdx.y;
#pragma unroll
  for (int i=0;i<4;i++){
    int r = r0 + ty + i*8;
    tile[ty+i*8][tx] = in[(size_t)r*C + c0 + tx];
  }
  __syncthreads();
#pragma unroll
  for (int i=0;i<4;i++){
    int cc = c0 + ty + i*8, rr = r0 + tx;
    float v = tile[tx][ty+i*8];
    if (MODE==1)      ((u16*)out)[(size_t)cc*R + rr] = f2h(v);
    else if (MODE==2) ((u16*)out)[(size_t)cc*R + rr] = f2b(v);
    else              ((float*)out)[(size_t)cc*R + rr] = v;
  }
}

__global__ __launch_bounds__(256) void transpose_all_kernel(
    const float* __restrict__ Wq, const float* __restrict__ W1,
    const float* __restrict__ W2, const float* __restrict__ Wv,
    u16* __restrict__ Wqbt, u16* __restrict__ W116t,
    u16* __restrict__ W216t, float* __restrict__ WvT)
{
  __shared__ float tile[32][33];
  int bid = blockIdx.x;
  if (bid < 384){
    tr_tile<512,768,2>(Wq, Wqbt, bid%24, bid/24, tile);
  } else if (bid < 1408){
    int b = bid-384;  tr_tile<512,2048,1>(W1, W116t, b%64, b/64, tile);
  } else if (bid < 2432){
    int b = bid-1408; tr_tile<2048,512,1>(W2, W216t, b%16, b/16, tile);
  } else {
    int b = bid-2432; tr_tile<768,512,0>(Wv, WvT, b%16, b/16, tile);
  }
}

// ---------------------------------------------------------------------------
// Key stats
// ---------------------------------------------------------------------------
__global__ __launch_bounds__(256) void keystats_kernel(
    const float* __restrict__ text, const float* __restrict__ bq,
    float* __restrict__ normk, float* __restrict__ crr)
{
  int gw = blockIdx.x*4 + (threadIdx.x>>6);
  int lane = threadIdx.x & 63;
  const float* tr = &text[(size_t)gw*TDIM];
  double ss=0.0, db=0.0;
#pragma unroll
  for (int i=0;i<12;i++){
    float v = tr[lane + 64*i];
    ss += (double)v*(double)v;
    db += (double)bq[lane+64*i]*(double)v;
  }
  ss = wsumd(ss); db = wsumd(db);
  if (lane==0){
    double nk = sqrt(ss); nk = nk>1e-12 ? nk : 1e-12;
    normk[gw] = (float)nk;
    crr[gw]   = (float)db;
  }
}

// ---------------------------------------------------------------------------
// LN1: writes split-bf16 planes visH + visL
// ---------------------------------------------------------------------------
__global__ __launch_bounds__(256) void ln1_kernel(
    const float* __restrict__ visual, const float* __restrict__ g1, const float* __restrict__ be1,
    u16* __restrict__ visH, u16* __restrict__ visL)
{
  int row = blockIdx.x*4 + (threadIdx.x>>6);
  int lane = threadIdx.x & 63;
  size_t base = (size_t)row*CDIM + lane*8;
  f32x4 a = *(const f32x4*)&visual[base];
  f32x4 c = *(const f32x4*)&visual[base+4];
  float s = a[0]+a[1]+a[2]+a[3]+c[0]+c[1]+c[2]+c[3];
  s = wsumf(s);
  float mu = s * (1.0f/512.0f);
  float q = 0.f;
#pragma unroll
  for (int i=0;i<4;i++){ float d=a[i]-mu; q+=d*d; }
#pragma unroll
  for (int i=0;i<4;i++){ float d=c[i]-mu; q+=d*d; }
  q = wsumf(q);
  float rs = rsqrtf(q*(1.0f/512.0f) + LN_EPS_);
  int cb = lane*8;
  float o[8];
#pragma unroll
  for (int i=0;i<4;i++) o[i]   = (a[i]-mu)*rs*g1[cb+i]   + be1[cb+i];
#pragma unroll
  for (int i=0;i<4;i++) o[4+i] = (c[i]-mu)*rs*g1[cb+4+i] + be1[cb+4+i];
  u16 hh[8];
  float lo[8];
#pragma unroll
  for (int i=0;i<8;i++){ hh[i] = f2b(o[i]); lo[i] = o[i] - b2f(hh[i]); }
  u32x4 hv, lv;
#pragma unroll
  for (int i=0;i<4;i++){
    hv[i] = (u32)hh[2*i] | ((u32)hh[2*i+1]<<16);
    lv[i] = pkb(lo[2*i], lo[2*i+1]);
  }
  *(u32x4*)&visH[base] = hv;
  *(u32x4*)&visL[base] = lv;
}

// ---------------------------------------------------------------------------
// fp32 GEMM (batched, small): Mrt and value only
// ---------------------------------------------------------------------------
__global__ __launch_bounds__(256) void gemm_f32_kernel(
    const float* __restrict__ A, const float* __restrict__ Bt, float* __restrict__ C,
    int M, int N, int K, long sA, long sB, long sC)
{
  __shared__ float As[64][17];
  __shared__ float Bs[64][17];
  const int z = blockIdx.z;
  A  += (size_t)z * sA; Bt += (size_t)z * sB; C += (size_t)z * sC;
  const int tid = threadIdx.x;
  const int tx = tid & 15, ty = tid >> 4;
  const int m0 = blockIdx.x*64, n0 = blockIdx.y*64;
  float acc[4][4];
#pragma unroll
  for (int i=0;i<4;i++)
#pragma unroll
    for (int j=0;j<4;j++) acc[i][j]=0.f;
  const int lr = tid >> 2, lc = (tid & 3)*4;
  for (int k0=0; k0<K; k0+=16){
    f32x4 av = *(const f32x4*)&A [(size_t)(m0+lr)*K + k0 + lc];
    f32x4 bv = *(const f32x4*)&Bt[(size_t)(n0+lr)*K + k0 + lc];
#pragma unroll
    for (int i=0;i<4;i++){ As[lr][lc+i]=av[i]; Bs[lr][lc+i]=bv[i]; }
    __syncthreads();
#pragma unroll
    for (int kk=0; kk<16; kk++){
      float a[4], b[4];
#pragma unroll
      for (int i=0;i<4;i++){ a[i]=As[ty*4+i][kk]; b[i]=Bs[tx*4+i][kk]; }
#pragma unroll
      for (int i=0;i<4;i++)
#pragma unroll
        for (int j=0;j<4;j++) acc[i][j] = fmaf(a[i], b[j], acc[i][j]);
    }
    __syncthreads();
  }
#pragma unroll
  for (int i=0;i<4;i++){
    f32x4 o;
#pragma unroll
    for (int j=0;j<4;j++) o[j]=acc[i][j];
    *(f32x4*)&C[(size_t)(m0+ty*4+i)*N + n0 + tx*4] = o;
  }
}

// ---------------------------------------------------------------------------
// Elementwise split fp32 -> bf16 hi + lo (for Mrt)
// ---------------------------------------------------------------------------
__global__ __launch_bounds__(256) void split_kernel(
    const float* __restrict__ in, u16* __restrict__ hi, u16* __restrict__ lo, int n4)
{
  int i = blockIdx.x*256 + threadIdx.x;
  if (i >= n4) return;
  f32x4 v = *(const f32x4*)&in[i*4];
  u32 hw[2], lw[2];
#pragma unroll
  for (int j=0;j<2;j++){
    u16 h0 = f2b(v[2*j]), h1 = f2b(v[2*j+1]);
    hw[j] = (u32)h0 | ((u32)h1<<16);
    lw[j] = pkb(v[2*j]-b2f(h0), v[2*j+1]-b2f(h1));
  }
  ((u32*)hi)[i*2]   = hw[0]; ((u32*)hi)[i*2+1] = hw[1];
  ((u32*)lo)[i*2]   = lw[0]; ((u32*)lo)[i*2+1] = lw[1];
}

// ---------------------------------------------------------------------------
// Fast exact-GELU (A&S 7.1.26 erf)
// ---------------------------------------------------------------------------
__device__ __forceinline__ float gelu_exact(float v){
  float x  = v*0.70710678118654752440f;
  float ax = fabsf(x);
  float t  = fast_rcp(fmaf(0.3275911f, ax, 1.0f));
  float p  = t*fmaf(t, fmaf(t, fmaf(t, fmaf(t, 1.061405429f, -1.453152027f),
                  1.421413741f), -0.284496736f), 0.254829592f);
  float e  = fast_exp2(ax*ax*(-1.4426950408889634f));
  float y  = 1.0f - p*e;
  float er = (x < 0.0f) ? -y : y;
  return 0.5f*v*(1.0f + er);
}

// ---------------------------------------------------------------------------
// 256²-tile 8-phase f16/bf16 MFMA GEMM, 512 thr (8 waves, 2M x 4N).
// dbuf + counted vmcnt (verified R7/R8), granule-XOR swizzle, XCD-chunked
// grid, per-tile: B-frag preload then 4 phases of {4 A-ds_read -> barrier ->
// setprio(1) -> 16 MFMA -> setprio(0) -> barrier}  (T3+T4+T5 interleave).
// EPI 0: bf16, row sum-of-squares -> out_f[row][ntile*4+wc]
// EPI 1: f16 gelu(acc+bias) -> f16 out_h
// EPI 2: f16 acc+bias+h2f(add_h) -> fp32 out_f
// ---------------------------------------------------------------------------
template<int EPI, int NN, int KK, int NT>
__global__ __launch_bounds__(512, 1) void gemm_big_kernel(
    const u16* __restrict__ A, const u16* __restrict__ Bt,
    const float* __restrict__ bias,
    float* __restrict__ out_f,
    u16* __restrict__ out_h,
    const u16* __restrict__ add_h)
{
  __shared__ __align__(16) u16 As[2][256*64];
  __shared__ __align__(16) u16 Bs[2][256*64];
  const int tid = threadIdx.x;
  const int lane = tid & 63, w = tid >> 6;      // 8 waves
  const int wr = w >> 2, wc = w & 3;            // 2 x 4
  constexpr int NWG = 128*NT;
  const int wg = blockIdx.x;
  const int b2 = (wg & 7)*(NWG/8) + (wg >> 3);
  const int ntile = b2 % NT, mtile = b2 / NT;
  const int m0 = mtile*256, n0 = ntile*256;
  f32x4 acc[8][4];
#pragma unroll
  for (int i=0;i<8;i++)
#pragma unroll
    for (int j=0;j<4;j++) acc[i][j] = (f32x4)0.f;
  const int lr = lane & 15, lk = (lane >> 4)*8;
  const int c8_sw = ((lane & 7) ^ (lane >> 3))*8;
  const size_t stride64 = (size_t)64*KK;
  const u16* aBase = &A [(size_t)(m0 + w*8 + (lane>>3))*KK + c8_sw];
  const u16* bBase = &Bt[(size_t)(n0 + w*8 + (lane>>3))*KK + c8_sw];

  auto STAGE = [&](int buf, int k0){
#pragma unroll
    for (int i=0;i<4;i++){
      gl_lds16(aBase + i*stride64 + k0, &As[buf][w*512 + i*4096]);
      gl_lds16(bBase + i*stride64 + k0, &Bs[buf][w*512 + i*4096]);
    }
  };

  STAGE(0, 0);
  int cur = 0;
  for (int k0=0; k0<KK; k0+=64){
    if (k0 + 64 < KK){
      STAGE(cur^1, k0+64);                               // issue next tile
      asm volatile("s_waitcnt vmcnt(8)" ::: "memory");   // tile-cur complete
    } else {
      asm volatile("s_waitcnt vmcnt(0)" ::: "memory");
    }
    __builtin_amdgcn_s_barrier();                        // LDS cur published
    // B-fragment preload (reused across the 4 phases)
    s16x8 bfv[4][2];
#pragma unroll
    for (int ni=0;ni<4;ni++)
#pragma unroll
      for (int kh=0;kh<2;kh++){
        const int csw = (kh*32 + lk) ^ ((lr & 7) << 3);
        bfv[ni][kh] = *(const s16x8*)&Bs[cur][(wc*64 + ni*16 + lr)*64 + csw];
      }
    // 4 phases: 2 M-frags each, 16 MFMA per phase
#pragma unroll
    for (int q=0;q<4;q++){
      s16x8 af[2][2];
#pragma unroll
      for (int m2=0;m2<2;m2++)
#pragma unroll
        for (int kh=0;kh<2;kh++){
          const int csw = (kh*32 + lk) ^ ((lr & 7) << 3);
          af[m2][kh] = *(const s16x8*)&As[cur][(wr*128 + (q*2+m2)*16 + lr)*64 + csw];
        }
      __builtin_amdgcn_s_barrier();                      // phase lead barrier
      __builtin_amdgcn_s_setprio(1);
#pragma unroll
      for (int m2=0;m2<2;m2++)
#pragma unroll
        for (int ni=0;ni<4;ni++)
#pragma unroll
          for (int kh=0;kh<2;kh++){
            if (EPI == 0)
              acc[q*2+m2][ni] = __builtin_amdgcn_mfma_f32_16x16x32_bf16(
                  af[m2][kh], bfv[ni][kh], acc[q*2+m2][ni], 0, 0, 0);
            else
              acc[q*2+m2][ni] = __builtin_amdgcn_mfma_f32_16x16x32_f16(
                  __builtin_bit_cast(f16x8, af[m2][kh]),
                  __builtin_bit_cast(f16x8, bfv[ni][kh]), acc[q*2+m2][ni], 0, 0, 0);
          }
      __builtin_amdgcn_s_setprio(0);
      __builtin_amdgcn_s_barrier();                      // phase tail barrier
    }
    cur ^= 1;
  }
  const int lr4 = (lane >> 4)*4;
  if (EPI == 0){
    float sq[8][4];
#pragma unroll
    for (int mi=0;mi<8;mi++)
#pragma unroll
      for (int r=0;r<4;r++) sq[mi][r]=0.f;
#pragma unroll
    for (int ni=0;ni<4;ni++){
      float bqv = bias[n0 + wc*64 + ni*16 + lr];
#pragma unroll
      for (int mi=0;mi<8;mi++)
#pragma unroll
        for (int r=0;r<4;r++){
          float v = acc[mi][ni][r] + bqv;
          sq[mi][r] += v*v;
        }
    }
#pragma unroll
    for (int o=1;o<16;o<<=1)
#pragma unroll
      for (int mi=0;mi<8;mi++)
#pragma unroll
        for (int r=0;r<4;r++) sq[mi][r] += __shfl_xor(sq[mi][r], o);
    if ((lane & 15) == 0){
      int part = ntile*4 + wc;
#pragma unroll
      for (int mi=0;mi<8;mi++)
#pragma unroll
        for (int r=0;r<4;r++){
          int row = m0 + wr*128 + mi*16 + lr4 + r;
          out_f[(size_t)row*12 + part] = sq[mi][r];
        }
    }
  } else {
    const int row0 = m0 + wr*128 + lr4;
    const int col0 = n0 + wc*64 + lr;
    float bb[4];
#pragma unroll
    for (int ni=0;ni<4;ni++) bb[ni] = bias[col0 + ni*16];
    if (EPI == 1){
      u16* op = out_h + (size_t)row0*NN + col0;
#pragma unroll
      for (int mi=0;mi<8;mi++)
#pragma unroll
        for (int r=0;r<4;r++)
#pragma unroll
          for (int ni=0;ni<4;ni++)
            op[(size_t)(mi*16+r)*NN + ni*16] = f2h(gelu_exact(acc[mi][ni][r] + bb[ni]));
    } else {
      float* op = out_f + (size_t)row0*NN + col0;
      const u16* rp = add_h + (size_t)row0*NN + col0;
#pragma unroll
      for (int mi=0;mi<8;mi++)
#pragma unroll
        for (int r=0;r<4;r++)
#pragma unroll
          for (int ni=0;ni<4;ni++)
            op[(size_t)(mi*16+r)*NN + ni*16] =
                acc[mi][ni][r] + bb[ni] + h2f(rp[(size_t)(mi*16+r)*NN + ni*16]);
    }
  }
}

// ---------------------------------------------------------------------------
// t = LN(vis) @ Mrt^T via split-bf16 MFMA, 3 passes (unchanged, verified R7).
// ---------------------------------------------------------------------------
__global__ __launch_bounds__(256) void gemm_t_kernel(
    const u16* __restrict__ Ah, const u16* __restrict__ Al,
    const u16* __restrict__ Bh, const u16* __restrict__ Bl,
    float* __restrict__ C)
{
  __shared__ __align__(16) u16 As[2][128*64];
  __shared__ __align__(16) u16 Bs[2][128*64];
  const int tid = threadIdx.x;
  const int lane = tid & 63, w = tid >> 6;
  const int wr = w >> 1, wc = w & 1;
  const int mtile = blockIdx.x;
  const int m0 = mtile*128, z = mtile >> 5;
  f32x4 acc[4][4];
#pragma unroll
  for (int i=0;i<4;i++)
#pragma unroll
    for (int j=0;j<4;j++) acc[i][j] = (f32x4)0.f;
  const int lr = lane & 15, lk = (lane >> 4)*8;
  const int c8_sw = ((lane & 7) ^ (lane >> 3))*8;
  const size_t aOff = (size_t)(m0 + w*8 + (lane>>3))*CDIM + c8_sw;
  const size_t bOff = (size_t)(z*KKEY + w*8 + (lane>>3))*CDIM + c8_sw;
  const size_t stride32 = (size_t)32*CDIM;

  auto STAGE = [&](int buf, int s){
    const int p = s >> 3, k0 = (s & 7) << 6;
    const u16* Ap = (p==2) ? Al : Ah;
    const u16* Bp = (p==1) ? Bl : Bh;
#pragma unroll
    for (int i=0;i<4;i++){
      gl_lds16(Ap + aOff + i*stride32 + k0, &As[buf][w*512 + i*2048]);
      gl_lds16(Bp + bOff + i*stride32 + k0, &Bs[buf][w*512 + i*2048]);
    }
  };

  STAGE(0, 0);
  int cur = 0;
  for (int s=0; s<24; ++s){
    if (s < 23){
      STAGE(cur^1, s+1);
      asm volatile("s_waitcnt vmcnt(8)" ::: "memory");
    } else {
      asm volatile("s_waitcnt vmcnt(0)" ::: "memory");
    }
    __builtin_amdgcn_s_barrier();
#pragma unroll
    for (int kk=0; kk<64; kk+=32){
      s16x8 af[4], bfv[4];
      const int csw = (kk + lk) ^ ((lr & 7) << 3);
#pragma unroll
      for (int mi=0;mi<4;mi++) af[mi]  = *(const s16x8*)&As[cur][(wr*64 + mi*16 + lr)*64 + csw];
#pragma unroll
      for (int ni=0;ni<4;ni++) bfv[ni] = *(const s16x8*)&Bs[cur][(wc*64 + ni*16 + lr)*64 + csw];
#pragma unroll
      for (int mi=0;mi<4;mi++)
#pragma unroll
        for (int ni=0;ni<4;ni++)
          acc[mi][ni] = __builtin_amdgcn_mfma_f32_16x16x32_bf16(af[mi], bfv[ni], acc[mi][ni], 0, 0, 0);
    }
    __builtin_amdgcn_s_barrier();
    cur ^= 1;
  }
  const int lr4 = (lane >> 4)*4;
  const int row0 = m0 + wr*64 + lr4;
  const int col0 = wc*64 + lr;
  float* op = C + (size_t)row0*KKEY + col0;
#pragma unroll
  for (int mi=0;mi<4;mi++)
#pragma unroll
    for (int r=0;r<4;r++)
#pragma unroll
      for (int ni=0;ni<4;ni++)
        op[(size_t)(mi*16+r)*KKEY + ni*16] = acc[mi][ni][r];
}

// ---------------------------------------------------------------------------
// fp64 rescue, one block per row
// ---------------------------------------------------------------------------
__global__ __launch_bounds__(256) void rescue_kernel(
    const int* __restrict__ rcnt, const int* __restrict__ rlist,
    const float* __restrict__ visual, const float* __restrict__ text,
    const float* __restrict__ Wq, const float* __restrict__ bq,
    const float* __restrict__ g1, const float* __restrict__ be1,
    const float* __restrict__ g2, const float* __restrict__ be2,
    const float* __restrict__ value, const float* __restrict__ bv,
    u16* __restrict__ fused16)
{
  __shared__ double vis64[512];
  __shared__ double q64[768];
  __shared__ double sims[128];
  __shared__ double pw[128];
  __shared__ double red[4];
  __shared__ double sc2[2];
  __shared__ int klist[128];
  __shared__ int kcount;
  const int tid = threadIdx.x, lane = tid & 63, w = tid >> 6;
  int n = *rcnt; if (n > NROWS) n = NROWS;
  for (int i = blockIdx.x; i < n; i += gridDim.x){
    const int row = rlist[i], b = row >> 12;
    const size_t rb = (size_t)row*CDIM;
    double x0 = (double)visual[rb+tid], x1 = (double)visual[rb+tid+256];
    double s = blocksumd4(x0+x1, red);
    double mu = s*(1.0/512.0);
    double d0 = x0-mu, d1 = x1-mu;
    double var = blocksumd4(d0*d0+d1*d1, red);
    double rs = 1.0/sqrt(var*(1.0/512.0) + 1e-5);
    vis64[tid]     = d0*rs*(double)g1[tid]     + (double)be1[tid];
    vis64[tid+256] = d1*rs*(double)g1[tid+256] + (double)be1[tid+256];
    __syncthreads();
    double qa0=(double)bq[tid], qa1=(double)bq[tid+256], qa2=(double)bq[tid+512];
#pragma unroll 4
    for (int c=0;c<CDIM;c++){
      double v = vis64[c];
      const float* wrow = &Wq[(size_t)c*TDIM];
      qa0 += v*(double)wrow[tid];
      qa1 += v*(double)wrow[tid+256];
      qa2 += v*(double)wrow[tid+512];
    }
    q64[tid]=qa0; q64[tid+256]=qa1; q64[tid+512]=qa2;
    double nq2 = blocksumd4(qa0*qa0+qa1*qa1+qa2*qa2, red);
    double nq = sqrt(nq2); if (nq < 1e-12) nq = 1e-12;
    __syncthreads();
    if (tid < KKEY){
      const float* trow = &text[((size_t)b*KKEY + tid)*TDIM];
      double dot=0.0, nk2=0.0;
#pragma unroll 8
      for (int j=0;j<TDIM;j++){
        double tv = (double)trow[j];
        dot += q64[j]*tv; nk2 += tv*tv;
      }
      double nk = sqrt(nk2); if (nk < 1e-12) nk = 1e-12;
      sims[tid] = dot/(nq*nk);
    }
    __syncthreads();
    if (w == 0){
      double v0=sims[lane], v1=sims[lane+64];
      bool rm0=false, rm1=false;
      double thr=0.0, smax=0.0;
      for (int it=0; it<5; ++it){
        double c0 = rm0 ? -1e300 : v0;
        double c1 = rm1 ? -1e300 : v1;
        double m = wmaxd(c0>c1 ? c0 : c1);
        if (it==0) smax = m;
        thr = m;
        bool h0 = (!rm0) && (v0==m);
        u64 k0 = __ballot(h0);
        if (k0){ if (lane == __ffsll(k0)-1) rm0 = true; }
        else {
          bool h1 = (!rm1) && (v1==m);
          u64 k1 = __ballot(h1);
          if (lane == __ffsll(k1)-1) rm1 = true;
        }
      }
      if (lane==0){ sc2[0]=smax; sc2[1]=thr; kcount=0; }
    }
    __syncthreads();
    const double smax = sc2[0], thr = sc2[1];
    double p = 0.0;
    if (tid < KKEY){
      double sv = sims[tid];
      p = (sv >= thr) ? exp((sv-smax)*(1.0/0.07)) : 0.0;
      pw[tid] = p;
      if (p > 0.0){ int pos = atomicAdd(&kcount, 1); klist[pos] = tid; }
    }
    double Z = blocksumd4(p, red);
    double zi = 1.0/Z;
    __syncthreads();
    double a0=(double)bv[tid], a1=(double)bv[tid+256];
    int kc = kcount;
    for (int ki=0; ki<kc; ++ki){
      int k = klist[ki];
      double wt = pw[k]*zi;
      const float* vr = &value[((size_t)b*KKEY + k)*CDIM];
      a0 += wt*(double)vr[tid];
      a1 += wt*(double)vr[tid+256];
    }
    double f0 = (double)visual[rb+tid]     + a0;
    double f1 = (double)visual[rb+tid+256] + a1;
    double fsum = blocksumd4(f0+f1, red);
    double fmu = fsum*(1.0/512.0);
    double e0=f0-fmu, e1=f1-fmu;
    double fvar = blocksumd4(e0*e0+e1*e1, red);
    double frs = 1.0/sqrt(fvar*(1.0/512.0) + 1e-5);
    fused16[rb+tid]     = f2h((float)(e0*frs*(double)g2[tid]     + (double)be2[tid]));
    fused16[rb+tid+256] = f2h((float)(e1*frs*(double)g2[tid+256] + (double)be2[tid+256]));
    __syncthreads();
  }
}

// ---------------------------------------------------------------------------
// Attention + residual + LN2: one wave per row, no LDS.
// ---------------------------------------------------------------------------
__global__ __launch_bounds__(256) void attn_ln2_kernel(
    const float* __restrict__ visual,
    const float* __restrict__ tbuf, const float* __restrict__ crr,
    const float* __restrict__ normk, const float* __restrict__ qpart,
    const float* __restrict__ value, const float* __restrict__ bv,
    const float* __restrict__ g2, const float* __restrict__ be2,
    u16* __restrict__ fused16,
    int* __restrict__ rcnt, int* __restrict__ rlist)
{
  const int w = threadIdx.x >> 6, lane = threadIdx.x & 63;
  const int row = blockIdx.x*4 + w;
  const int b = row >> 12;
  float nqp = (lane < 12) ? qpart[(size_t)row*12 + lane] : 0.f;
  float nq2 = wsumf(nqp);
  float nq = fmaxf(sqrtf(nq2), 1e-12f);
  const float* trow = &tbuf[(size_t)row*KKEY];
  float s0 = (trow[lane]    + crr[b*KKEY + lane])    / (nq*normk[b*KKEY + lane]);
  float s1 = (trow[lane+64] + crr[b*KKEY + lane+64]) / (nq*normk[b*KKEY + lane+64]);
  float v0=s0, v1=s1; bool rm0=false, rm1=false;
  float thr=0.f, smax=0.f, m6=0.f;
  for (int it=0; it<6; ++it){
    float c0 = rm0 ? -1e30f : v0;
    float c1 = rm1 ? -1e30f : v1;
    float m = wmaxf(fmaxf(c0,c1));
    if (it==0) smax = m;
    if (it<5){
      thr = m;
      bool h0 = (!rm0) && (v0==m);
      u64 k0 = __ballot(h0);
      if (k0){ if (lane == __ffsll(k0)-1) rm0 = true; }
      else {
        bool h1 = (!rm1) && (v1==m);
        u64 k1 = __ballot(h1);
        if (lane == __ffsll(k1)-1) rm1 = true;
      }
    } else m6 = m;
  }
  if ((thr - m6) < RESCUE_MARGIN){
    if (lane == 0){
      int p = atomicAdd(rcnt, 1);
      rlist[p] = row;
    }
    return;
  }
  float p0 = (s0>=thr) ? expf((s0-smax)*TINV) : 0.f;
  float p1 = (s1>=thr) ? expf((s1-smax)*TINV) : 0.f;
  float Z = wsumf(p0+p1);
  float zi = 1.f/Z;
  float accv[8];
#pragma unroll
  for (int j=0;j<8;j++) accv[j] = bv[lane*8+j];
  u64 mk0 = __ballot(p0>0.f);
  u64 mk1 = __ballot(p1>0.f);
  while (mk0){
    int l = __ffsll(mk0)-1; mk0 &= mk0-1;
    float wt = __shfl(p0, l)*zi;
    const f32x4* vr = (const f32x4*)&value[((size_t)b*KKEY + l)*CDIM + lane*8];
    f32x4 va = vr[0], vb = vr[1];
#pragma unroll
    for (int j=0;j<4;j++){ accv[j] += wt*va[j]; accv[4+j] += wt*vb[j]; }
  }
  while (mk1){
    int l = __ffsll(mk1)-1; mk1 &= mk1-1;
    float wt = __shfl(p1, l)*zi;
    const f32x4* vr = (const f32x4*)&value[((size_t)b*KKEY + l + 64)*CDIM + lane*8];
    f32x4 va = vr[0], vb = vr[1];
#pragma unroll
    for (int j=0;j<4;j++){ accv[j] += wt*va[j]; accv[4+j] += wt*vb[j]; }
  }
  size_t rb = (size_t)row*CDIM + lane*8;
  f32x4 r0v = *(const f32x4*)&visual[rb];
  f32x4 r1v = *(const f32x4*)&visual[rb+4];
  float f[8];
#pragma unroll
  for (int j=0;j<4;j++){ f[j]=r0v[j]+accv[j]; f[4+j]=r1v[j]+accv[4+j]; }
  float fs=0.f;
#pragma unroll
  for (int j=0;j<8;j++) fs += f[j];
  fs = wsumf(fs);
  float fmu = fs*(1.0f/512.0f);
  float fvv=0.f;
#pragma unroll
  for (int j=0;j<8;j++){ float d=f[j]-fmu; fvv+=d*d; }
  fvv = wsumf(fvv);
  float frs = rsqrtf(fvv*(1.0f/512.0f) + LN_EPS_);
  int cb = lane*8;
  f32x4 o0,o1;
#pragma unroll
  for (int j=0;j<4;j++) o0[j] = (f[j]-fmu)*frs*g2[cb+j]     + be2[cb+j];
#pragma unroll
  for (int j=0;j<4;j++) o1[j] = (f[4+j]-fmu)*frs*g2[cb+4+j] + be2[cb+4+j];
  u32x4 hv;
  hv[0]=pk2(o0[0],o0[1]); hv[1]=pk2(o0[2],o0[3]);
  hv[2]=pk2(o1[0],o1[1]); hv[3]=pk2(o1[2],o1[3]);
  *(u32x4*)&fused16[rb] = hv;
}

// ---------------------------------------------------------------------------
extern "C" void kernel_launch(void* const* d_in, const int* in_sizes, int n_in,
                              void* d_out, int out_size, void* d_ws, size_t ws_size,
                              hipStream_t stream)
{
  (void)in_sizes; (void)n_in; (void)out_size; (void)ws_size;
  const float* visual = (const float*)d_in[0];
  const float* text   = (const float*)d_in[1];
  const float* Wq     = (const float*)d_in[2];
  const float* bq     = (const float*)d_in[3];
  const float* Wv     = (const float*)d_in[4];
  const float* bv     = (const float*)d_in[5];
  const float* W1     = (const float*)d_in[6];
  const float* b1     = (const float*)d_in[7];
  const float* W2     = (const float*)d_in[8];
  const float* b2     = (const float*)d_in[9];
  const float* g1     = (const float*)d_in[10];
  const float* be1    = (const float*)d_in[11];
  const float* g2     = (const float*)d_in[12];
  const float* be2    = (const float*)d_in[13];
  float* out = (float*)d_out;

  char* ws = (char*)d_ws;
  size_t off = 0;
  auto alloc = [&](size_t bytes)->char*{
    char* p = ws + off; off += (bytes + 255) & ~(size_t)255; return p; };

  u16*    visH   = (u16*)   alloc((size_t)NROWS*CDIM*2);
  u16*    visL   = (u16*)   alloc((size_t)NROWS*CDIM*2);
  u16*    h16    = (u16*)   alloc((size_t)NROWS*FFDIM*2);
  u16*    fused16= (u16*)   alloc((size_t)NROWS*CDIM*2);
  float*  tbuf   = (float*) alloc((size_t)NROWS*KKEY*4);
  float*  Mrt    = (float*) alloc((size_t)NB*KKEY*CDIM*4);
  u16*    MrtH   = (u16*)   alloc((size_t)NB*KKEY*CDIM*2);
  u16*    MrtL   = (u16*)   alloc((size_t)NB*KKEY*CDIM*2);
  float*  value  = (float*) alloc((size_t)NB*KKEY*CDIM*4);
  u16*    Wqbt   = (u16*)   alloc((size_t)TDIM*CDIM*2);
  u16*    W116t  = (u16*)   alloc((size_t)FFDIM*CDIM*2);
  u16*    W216t  = (u16*)   alloc((size_t)CDIM*FFDIM*2);
  float*  WvT    = (float*) alloc((size_t)CDIM*TDIM*4);
  float*  qpart  = (float*) alloc((size_t)NROWS*12*4);
  float*  normk  = (float*) alloc((size_t)NB*KKEY*4);
  float*  crr    = (float*) alloc((size_t)NB*KKEY*4);
  int*    rcnt   = (int*)   alloc(256);
  int*    rlist  = (int*)   alloc((size_t)NROWS*4);

  hipMemsetAsync(rcnt, 0, sizeof(int), stream);

  transpose_all_kernel<<<2816, dim3(32,8), 0, stream>>>(
      Wq, W1, W2, Wv, Wqbt, W116t, W216t, WvT);
  keystats_kernel<<<256, 256, 0, stream>>>(text, bq, normk, crr);
  gemm_f32_kernel<<<dim3(2, 8, 8), 256, 0, stream>>>(
      text, Wq, Mrt, KKEY, CDIM, TDIM, (long)KKEY*TDIM, 0, (long)KKEY*CDIM);
  gemm_f32_kernel<<<dim3(2, 8, 8), 256, 0, stream>>>(
      text, WvT, value, KKEY, CDIM, TDIM, (long)KKEY*TDIM, 0, (long)KKEY*CDIM);
  split_kernel<<<512, 256, 0, stream>>>(Mrt, MrtH, MrtL, NB*KKEY*CDIM/4);
  ln1_kernel<<<NROWS/4, 256, 0, stream>>>(visual, g1, be1, visH, visL);
  gemm_t_kernel<<<256, 256, 0, stream>>>(visH, visL, MrtH, MrtL, tbuf);
  // qnorm: 256² 8-phase bf16, NT=3 -> grid 384
  gemm_big_kernel<0,TDIM,CDIM,3><<<384, 512, 0, stream>>>(
      visH, Wqbt, bq, qpart, nullptr, nullptr);
  attn_ln2_kernel<<<NROWS/4, 256, 0, stream>>>(
      visual, tbuf, crr, normk, qpart, value, bv, g2, be2,
      fused16, rcnt, rlist);
  rescue_kernel<<<256, 256, 0, stream>>>(
      rcnt, rlist, visual, text, Wq, bq, g1, be1, g2, be2, value, bv, fused16);
  // FFN1: 256² 8-phase, NT=8 -> grid 1024
  gemm_big_kernel<1,FFDIM,CDIM,8><<<1024, 512, 0, stream>>>(
      fused16, W116t, b1, nullptr, h16, nullptr);
  // FFN2: 256² 8-phase, NT=2 -> grid 256
  gemm_big_kernel<2,CDIM,FFDIM,2><<<256, 512, 0, stream>>>(
      h16, W216t, b2, out, nullptr, fused16);
}

// Round 10
// 458.587 us; speedup vs baseline: 1.2075x; 1.2075x over previous
//
#include <hip/hip_runtime.h>
#include <math.h>

typedef unsigned short u16;
typedef unsigned int   u32;
typedef unsigned long long u64;
typedef __attribute__((ext_vector_type(4))) float f32x4;
typedef __attribute__((ext_vector_type(4))) unsigned int u32x4;
typedef __attribute__((ext_vector_type(8))) _Float16 f16x8;
typedef __attribute__((ext_vector_type(8))) short s16x8;   // 8 bf16

#define NROWS   32768
#define CDIM    512
#define TDIM    768
#define KKEY    128
#define FFDIM   2048
#define NB      8
#define RPB     4096
#define LN_EPS_ 1e-5f
#define TINV    (1.0f/0.07f)
#define RESCUE_MARGIN 1e-5f

__device__ __forceinline__ u16 f2h(float f){ _Float16 h=(_Float16)f; return __builtin_bit_cast(u16,h); }
__device__ __forceinline__ float h2f(u16 v){ return (float)__builtin_bit_cast(_Float16, v); }
__device__ __forceinline__ unsigned pk2(float a,float b){ return (unsigned)f2h(a)|((unsigned)f2h(b)<<16); }
__device__ __forceinline__ u16 f2b(float f){
  u32 u = __builtin_bit_cast(u32, f);
  u32 r = (u + 0x7fffu + ((u>>16)&1u)) >> 16;
  return (u16)r;
}
__device__ __forceinline__ float b2f(u16 h){ u32 u = ((u32)h)<<16; return __builtin_bit_cast(float, u); }
__device__ __forceinline__ unsigned pkb(float a,float b){ return (unsigned)f2b(a)|((unsigned)f2b(b)<<16); }

__device__ __forceinline__ void gl_lds16(const void* g, void* l){
  __builtin_amdgcn_global_load_lds(
      (const __attribute__((address_space(1))) u32*)g,
      (__attribute__((address_space(3))) u32*)l, 16, 0, 0);
}

__device__ __forceinline__ float fast_exp2(float x){
#if __has_builtin(__builtin_amdgcn_exp2f)
  return __builtin_amdgcn_exp2f(x);
#else
  return exp2f(x);
#endif
}
__device__ __forceinline__ float fast_rcp(float x){
#if __has_builtin(__builtin_amdgcn_rcpf)
  return __builtin_amdgcn_rcpf(x);
#else
  return 1.0f/x;
#endif
}

__device__ __forceinline__ float wsumf(float v){
#pragma unroll
  for(int o=1;o<64;o<<=1) v+=__shfl_xor(v,o);
  return v; }
__device__ __forceinline__ float wmaxf(float v){
#pragma unroll
  for(int o=1;o<64;o<<=1) v=fmaxf(v,__shfl_xor(v,o));
  return v; }
__device__ __forceinline__ double wsumd(double v){
#pragma unroll
  for(int o=1;o<64;o<<=1) v+=__shfl_xor(v,o);
  return v; }
__device__ __forceinline__ double wmaxd(double v){
#pragma unroll
  for(int o=1;o<64;o<<=1){ double t=__shfl_xor(v,o); v = t>v ? t : v; }
  return v; }

__device__ __forceinline__ double blocksumd4(double v, double* red){
  const int lane = threadIdx.x & 63, w = threadIdx.x >> 6;
  v = wsumd(v);
  __syncthreads();
  if (lane==0) red[w] = v;
  __syncthreads();
  return red[0]+red[1]+red[2]+red[3];
}

// ---------------------------------------------------------------------------
// Unified weight transpose+cast. MODE: 0=f32, 1=f16, 2=bf16
// ---------------------------------------------------------------------------
template<int R, int C, int MODE>
__device__ __forceinline__ void tr_tile(const float* __restrict__ in, void* __restrict__ out,
                                        int bx, int by, float (*tile)[33])
{
  int c0 = bx*32, r0 = by*32;
  int tx = threadIdx.x, ty = threadIdx.y;
#pragma unroll
  for (int i=0;i<4;i++){
    int r = r0 + ty + i*8;
    tile[ty+i*8][tx] = in[(size_t)r*C + c0 + tx];
  }
  __syncthreads();
#pragma unroll
  for (int i=0;i<4;i++){
    int cc = c0 + ty + i*8, rr = r0 + tx;
    float v = tile[tx][ty+i*8];
    if (MODE==1)      ((u16*)out)[(size_t)cc*R + rr] = f2h(v);
    else if (MODE==2) ((u16*)out)[(size_t)cc*R + rr] = f2b(v);
    else              ((float*)out)[(size_t)cc*R + rr] = v;
  }
}

__global__ __launch_bounds__(256) void transpose_all_kernel(
    const float* __restrict__ Wq, const float* __restrict__ W1,
    const float* __restrict__ W2, const float* __restrict__ Wv,
    u16* __restrict__ Wqbt, u16* __restrict__ W116t,
    u16* __restrict__ W216t, float* __restrict__ WvT)
{
  __shared__ float tile[32][33];
  int bid = blockIdx.x;
  if (bid < 384){
    tr_tile<512,768,2>(Wq, Wqbt, bid%24, bid/24, tile);
  } else if (bid < 1408){
    int b = bid-384;  tr_tile<512,2048,1>(W1, W116t, b%64, b/64, tile);
  } else if (bid < 2432){
    int b = bid-1408; tr_tile<2048,512,1>(W2, W216t, b%16, b/16, tile);
  } else {
    int b = bid-2432; tr_tile<768,512,0>(Wv, WvT, b%16, b/16, tile);
  }
}

// ---------------------------------------------------------------------------
// Key stats
// ---------------------------------------------------------------------------
__global__ __launch_bounds__(256) void keystats_kernel(
    const float* __restrict__ text, const float* __restrict__ bq,
    float* __restrict__ normk, float* __restrict__ crr)
{
  int gw = blockIdx.x*4 + (threadIdx.x>>6);
  int lane = threadIdx.x & 63;
  const float* tr = &text[(size_t)gw*TDIM];
  double ss=0.0, db=0.0;
#pragma unroll
  for (int i=0;i<12;i++){
    float v = tr[lane + 64*i];
    ss += (double)v*(double)v;
    db += (double)bq[lane+64*i]*(double)v;
  }
  ss = wsumd(ss); db = wsumd(db);
  if (lane==0){
    double nk = sqrt(ss); nk = nk>1e-12 ? nk : 1e-12;
    normk[gw] = (float)nk;
    crr[gw]   = (float)db;
  }
}

// ---------------------------------------------------------------------------
// LN1: writes split-bf16 planes visH + visL
// ---------------------------------------------------------------------------
__global__ __launch_bounds__(256) void ln1_kernel(
    const float* __restrict__ visual, const float* __restrict__ g1, const float* __restrict__ be1,
    u16* __restrict__ visH, u16* __restrict__ visL)
{
  int row = blockIdx.x*4 + (threadIdx.x>>6);
  int lane = threadIdx.x & 63;
  size_t base = (size_t)row*CDIM + lane*8;
  f32x4 a = *(const f32x4*)&visual[base];
  f32x4 c = *(const f32x4*)&visual[base+4];
  float s = a[0]+a[1]+a[2]+a[3]+c[0]+c[1]+c[2]+c[3];
  s = wsumf(s);
  float mu = s * (1.0f/512.0f);
  float q = 0.f;
#pragma unroll
  for (int i=0;i<4;i++){ float d=a[i]-mu; q+=d*d; }
#pragma unroll
  for (int i=0;i<4;i++){ float d=c[i]-mu; q+=d*d; }
  q = wsumf(q);
  float rs = rsqrtf(q*(1.0f/512.0f) + LN_EPS_);
  int cb = lane*8;
  float o[8];
#pragma unroll
  for (int i=0;i<4;i++) o[i]   = (a[i]-mu)*rs*g1[cb+i]   + be1[cb+i];
#pragma unroll
  for (int i=0;i<4;i++) o[4+i] = (c[i]-mu)*rs*g1[cb+4+i] + be1[cb+4+i];
  u16 hh[8];
  float lo[8];
#pragma unroll
  for (int i=0;i<8;i++){ hh[i] = f2b(o[i]); lo[i] = o[i] - b2f(hh[i]); }
  u32x4 hv, lv;
#pragma unroll
  for (int i=0;i<4;i++){
    hv[i] = (u32)hh[2*i] | ((u32)hh[2*i+1]<<16);
    lv[i] = pkb(lo[2*i], lo[2*i+1]);
  }
  *(u32x4*)&visH[base] = hv;
  *(u32x4*)&visL[base] = lv;
}

// ---------------------------------------------------------------------------
// Merged text-side fp32 GEMM: z<8 -> Mrt[z] = text[z]@Wq^T (epilogue splits
// to bf16 hi/lo planes); z>=8 -> value[z-8] = text[z-8]@WvT^T (fp32).
// Grid (2, 8, 16): 256 blocks (2x occupancy vs two 128-block launches).
// ---------------------------------------------------------------------------
__global__ __launch_bounds__(256) void gemm_txt_kernel(
    const float* __restrict__ text, const float* __restrict__ Wq,
    const float* __restrict__ WvT,
    u16* __restrict__ MrtH, u16* __restrict__ MrtL, float* __restrict__ value)
{
  __shared__ float As[64][17];
  __shared__ float Bs[64][17];
  const int zz = blockIdx.z;
  const bool isV = zz >= 8;
  const int z = isV ? zz-8 : zz;
  const float* A  = text + (size_t)z*KKEY*TDIM;
  const float* Bt = isV ? WvT : Wq;          // both 512 x 768 (N x K)
  const int tid = threadIdx.x;
  const int tx = tid & 15, ty = tid >> 4;
  const int m0 = blockIdx.x*64, n0 = blockIdx.y*64;
  float acc[4][4];
#pragma unroll
  for (int i=0;i<4;i++)
#pragma unroll
    for (int j=0;j<4;j++) acc[i][j]=0.f;
  const int lr = tid >> 2, lc = (tid & 3)*4;
  for (int k0=0; k0<TDIM; k0+=16){
    f32x4 av = *(const f32x4*)&A [(size_t)(m0+lr)*TDIM + k0 + lc];
    f32x4 bv = *(const f32x4*)&Bt[(size_t)(n0+lr)*TDIM + k0 + lc];
#pragma unroll
    for (int i=0;i<4;i++){ As[lr][lc+i]=av[i]; Bs[lr][lc+i]=bv[i]; }
    __syncthreads();
#pragma unroll
    for (int kk=0; kk<16; kk++){
      float a[4], b[4];
#pragma unroll
      for (int i=0;i<4;i++){ a[i]=As[ty*4+i][kk]; b[i]=Bs[tx*4+i][kk]; }
#pragma unroll
      for (int i=0;i<4;i++)
#pragma unroll
        for (int j=0;j<4;j++) acc[i][j] = fmaf(a[i], b[j], acc[i][j]);
    }
    __syncthreads();
  }
#pragma unroll
  for (int i=0;i<4;i++){
    size_t idx = ((size_t)z*KKEY + m0 + ty*4 + i)*CDIM + n0 + tx*4;
    if (isV){
      f32x4 o;
#pragma unroll
      for (int j=0;j<4;j++) o[j]=acc[i][j];
      *(f32x4*)&value[idx] = o;
    } else {
      u16 hh[4]; u16 ll[4];
#pragma unroll
      for (int j=0;j<4;j++){
        float v = acc[i][j];
        u16 h = f2b(v);
        hh[j] = h;
        ll[j] = f2b(v - b2f(h));
      }
      ((u32*)&MrtH[idx])[0] = (u32)hh[0] | ((u32)hh[1]<<16);
      ((u32*)&MrtH[idx])[1] = (u32)hh[2] | ((u32)hh[3]<<16);
      ((u32*)&MrtL[idx])[0] = (u32)ll[0] | ((u32)ll[1]<<16);
      ((u32*)&MrtL[idx])[1] = (u32)ll[2] | ((u32)ll[3]<<16);
    }
  }
}

// ---------------------------------------------------------------------------
// Fast exact-GELU (A&S 7.1.26 erf)
// ---------------------------------------------------------------------------
__device__ __forceinline__ float gelu_exact(float v){
  float x  = v*0.70710678118654752440f;
  float ax = fabsf(x);
  float t  = fast_rcp(fmaf(0.3275911f, ax, 1.0f));
  float p  = t*fmaf(t, fmaf(t, fmaf(t, fmaf(t, 1.061405429f, -1.453152027f),
                  1.421413741f), -0.284496736f), 0.254829592f);
  float e  = fast_exp2(ax*ax*(-1.4426950408889634f));
  float y  = 1.0f - p*e;
  float er = (x < 0.0f) ? -y : y;
  return 0.5f*v*(1.0f + er);
}

// ---------------------------------------------------------------------------
// f16/bf16 MFMA GEMM (R7 best-measured config): 128² tile, dbuf LDS +
// counted vmcnt, granule-XOR swizzle, XCD-chunked grid.
// EPI 0 = bf16 row-sumsq (qnorm); EPI 1 = f16 gelu->f16; EPI 2 = f16
// +bias+residual->fp32.
// ---------------------------------------------------------------------------
template<int EPI, int NN, int KK, int NT>
__global__ __launch_bounds__(256) void gemm_f16_kernel(
    const u16* __restrict__ A, const u16* __restrict__ Bt,
    const float* __restrict__ bias,
    float* __restrict__ out_f,
    u16* __restrict__ out_h,
    const u16* __restrict__ add_h)
{
  __shared__ __align__(16) u16 As[2][128*64];
  __shared__ __align__(16) u16 Bs[2][128*64];
  const int tid = threadIdx.x;
  const int lane = tid & 63, w = tid >> 6;
  const int wr = w >> 1, wc = w & 1;
  constexpr int NWG = 256*NT;
  const int wg = blockIdx.x;
  const int b2 = (wg & 7)*(NWG/8) + (wg >> 3);
  const int ntile = b2 % NT, mtile = b2 / NT;
  const int m0 = mtile*128, n0 = ntile*128;
  f32x4 acc[4][4];
#pragma unroll
  for (int i=0;i<4;i++)
#pragma unroll
    for (int j=0;j<4;j++) acc[i][j] = (f32x4)0.f;
  const int lr = lane & 15, lk = (lane >> 4)*8;
  const int c8_sw = ((lane & 7) ^ (lane >> 3))*8;
  const size_t stride32 = (size_t)32*KK;
  const u16* aBase = &A [(size_t)(m0 + w*8 + (lane>>3))*KK + c8_sw];
  const u16* bBase = &Bt[(size_t)(n0 + w*8 + (lane>>3))*KK + c8_sw];

  auto STAGE = [&](int buf, int k0){
#pragma unroll
    for (int i=0;i<4;i++){
      gl_lds16(aBase + i*stride32 + k0, &As[buf][w*512 + i*2048]);
      gl_lds16(bBase + i*stride32 + k0, &Bs[buf][w*512 + i*2048]);
    }
  };

  STAGE(0, 0);
  int cur = 0;
  for (int k0=0; k0<KK; k0+=64){
    if (k0 + 64 < KK){
      STAGE(cur^1, k0+64);
      asm volatile("s_waitcnt vmcnt(8)" ::: "memory");
    } else {
      asm volatile("s_waitcnt vmcnt(0)" ::: "memory");
    }
    __builtin_amdgcn_s_barrier();
#pragma unroll
    for (int kk=0; kk<64; kk+=32){
      s16x8 af[4], bfv[4];
      const int csw = (kk + lk) ^ ((lr & 7) << 3);
#pragma unroll
      for (int mi=0;mi<4;mi++) af[mi]  = *(const s16x8*)&As[cur][(wr*64 + mi*16 + lr)*64 + csw];
#pragma unroll
      for (int ni=0;ni<4;ni++) bfv[ni] = *(const s16x8*)&Bs[cur][(wc*64 + ni*16 + lr)*64 + csw];
#pragma unroll
      for (int mi=0;mi<4;mi++)
#pragma unroll
        for (int ni=0;ni<4;ni++){
          if (EPI == 0)
            acc[mi][ni] = __builtin_amdgcn_mfma_f32_16x16x32_bf16(af[mi], bfv[ni], acc[mi][ni], 0, 0, 0);
          else
            acc[mi][ni] = __builtin_amdgcn_mfma_f32_16x16x32_f16(
                __builtin_bit_cast(f16x8, af[mi]), __builtin_bit_cast(f16x8, bfv[ni]), acc[mi][ni], 0, 0, 0);
        }
    }
    __builtin_amdgcn_s_barrier();
    cur ^= 1;
  }
  const int lr4 = (lane >> 4)*4;
  if (EPI == 0){
    float sq[4][4];
#pragma unroll
    for (int mi=0;mi<4;mi++)
#pragma unroll
      for (int r=0;r<4;r++) sq[mi][r]=0.f;
#pragma unroll
    for (int ni=0;ni<4;ni++){
      float bqv = bias[n0 + wc*64 + ni*16 + lr];
#pragma unroll
      for (int mi=0;mi<4;mi++)
#pragma unroll
        for (int r=0;r<4;r++){
          float v = acc[mi][ni][r] + bqv;
          sq[mi][r] += v*v;
        }
    }
#pragma unroll
    for (int o=1;o<16;o<<=1)
#pragma unroll
      for (int mi=0;mi<4;mi++)
#pragma unroll
        for (int r=0;r<4;r++) sq[mi][r] += __shfl_xor(sq[mi][r], o);
    if ((lane & 15) == 0){
      int part = ntile*2 + wc;
#pragma unroll
      for (int mi=0;mi<4;mi++)
#pragma unroll
        for (int r=0;r<4;r++){
          int row = m0 + wr*64 + mi*16 + lr4 + r;
          out_f[(size_t)row*12 + part] = sq[mi][r];
        }
    }
  } else {
    const int row0 = m0 + wr*64 + lr4;
    const int col0 = n0 + wc*64 + lr;
    float bb[4];
#pragma unroll
    for (int ni=0;ni<4;ni++) bb[ni] = bias[col0 + ni*16];
    if (EPI == 1){
      u16* op = out_h + (size_t)row0*NN + col0;
#pragma unroll
      for (int mi=0;mi<4;mi++)
#pragma unroll
        for (int r=0;r<4;r++)
#pragma unroll
          for (int ni=0;ni<4;ni++)
            op[(size_t)(mi*16+r)*NN + ni*16] = f2h(gelu_exact(acc[mi][ni][r] + bb[ni]));
    } else {
      float* op = out_f + (size_t)row0*NN + col0;
      const u16* rp = add_h + (size_t)row0*NN + col0;
#pragma unroll
      for (int mi=0;mi<4;mi++)
#pragma unroll
        for (int r=0;r<4;r++)
#pragma unroll
          for (int ni=0;ni<4;ni++)
            op[(size_t)(mi*16+r)*NN + ni*16] =
                acc[mi][ni][r] + bb[ni] + h2f(rp[(size_t)(mi*16+r)*NN + ni*16]);
    }
  }
}

// ---------------------------------------------------------------------------
// t-GEMM, split-bf16: pass p = blockIdx.y (0: AhBh, 1: AhBl, 2: AlBh)
// writes plane C + p*NROWS*KKEY. Grid (256, 3) = 768 blocks (3x TLP vs R7).
// attn sums the three planes in fixed order (deterministic).
// ---------------------------------------------------------------------------
__global__ __launch_bounds__(256) void gemm_t_kernel(
    const u16* __restrict__ Ah, const u16* __restrict__ Al,
    const u16* __restrict__ Bh, const u16* __restrict__ Bl,
    float* __restrict__ C)
{
  __shared__ __align__(16) u16 As[2][128*64];
  __shared__ __align__(16) u16 Bs[2][128*64];
  const int tid = threadIdx.x;
  const int lane = tid & 63, w = tid >> 6;
  const int wr = w >> 1, wc = w & 1;
  const int mtile = blockIdx.x;
  const int p = blockIdx.y;
  const int m0 = mtile*128, z = mtile >> 5;
  const u16* Ap = (p==2) ? Al : Ah;
  const u16* Bp = (p==1) ? Bl : Bh;
  f32x4 acc[4][4];
#pragma unroll
  for (int i=0;i<4;i++)
#pragma unroll
    for (int j=0;j<4;j++) acc[i][j] = (f32x4)0.f;
  const int lr = lane & 15, lk = (lane >> 4)*8;
  const int c8_sw = ((lane & 7) ^ (lane >> 3))*8;
  const size_t aOff = (size_t)(m0 + w*8 + (lane>>3))*CDIM + c8_sw;
  const size_t bOff = (size_t)(z*KKEY + w*8 + (lane>>3))*CDIM + c8_sw;
  const size_t stride32 = (size_t)32*CDIM;

  auto STAGE = [&](int buf, int s){
    const int k0 = s << 6;
#pragma unroll
    for (int i=0;i<4;i++){
      gl_lds16(Ap + aOff + i*stride32 + k0, &As[buf][w*512 + i*2048]);
      gl_lds16(Bp + bOff + i*stride32 + k0, &Bs[buf][w*512 + i*2048]);
    }
  };

  STAGE(0, 0);
  int cur = 0;
  for (int s=0; s<8; ++s){
    if (s < 7){
      STAGE(cur^1, s+1);
      asm volatile("s_waitcnt vmcnt(8)" ::: "memory");
    } else {
      asm volatile("s_waitcnt vmcnt(0)" ::: "memory");
    }
    __builtin_amdgcn_s_barrier();
#pragma unroll
    for (int kk=0; kk<64; kk+=32){
      s16x8 af[4], bfv[4];
      const int csw = (kk + lk) ^ ((lr & 7) << 3);
#pragma unroll
      for (int mi=0;mi<4;mi++) af[mi]  = *(const s16x8*)&As[cur][(wr*64 + mi*16 + lr)*64 + csw];
#pragma unroll
      for (int ni=0;ni<4;ni++) bfv[ni] = *(const s16x8*)&Bs[cur][(wc*64 + ni*16 + lr)*64 + csw];
#pragma unroll
      for (int mi=0;mi<4;mi++)
#pragma unroll
        for (int ni=0;ni<4;ni++)
          acc[mi][ni] = __builtin_amdgcn_mfma_f32_16x16x32_bf16(af[mi], bfv[ni], acc[mi][ni], 0, 0, 0);
    }
    __builtin_amdgcn_s_barrier();
    cur ^= 1;
  }
  const int lr4 = (lane >> 4)*4;
  const int row0 = m0 + wr*64 + lr4;
  const int col0 = wc*64 + lr;
  float* op = C + (size_t)p*NROWS*KKEY + (size_t)row0*KKEY + col0;
#pragma unroll
  for (int mi=0;mi<4;mi++)
#pragma unroll
    for (int r=0;r<4;r++)
#pragma unroll
      for (int ni=0;ni<4;ni++)
        op[(size_t)(mi*16+r)*KKEY + ni*16] = acc[mi][ni][r];
}

// ---------------------------------------------------------------------------
// fp64 rescue, one block per row
// ---------------------------------------------------------------------------
__global__ __launch_bounds__(256) void rescue_kernel(
    const int* __restrict__ rcnt, const int* __restrict__ rlist,
    const float* __restrict__ visual, const float* __restrict__ text,
    const float* __restrict__ Wq, const float* __restrict__ bq,
    const float* __restrict__ g1, const float* __restrict__ be1,
    const float* __restrict__ g2, const float* __restrict__ be2,
    const float* __restrict__ value, const float* __restrict__ bv,
    u16* __restrict__ fused16)
{
  __shared__ double vis64[512];
  __shared__ double q64[768];
  __shared__ double sims[128];
  __shared__ double pw[128];
  __shared__ double red[4];
  __shared__ double sc2[2];
  __shared__ int klist[128];
  __shared__ int kcount;
  const int tid = threadIdx.x, lane = tid & 63, w = tid >> 6;
  int n = *rcnt; if (n > NROWS) n = NROWS;
  for (int i = blockIdx.x; i < n; i += gridDim.x){
    const int row = rlist[i], b = row >> 12;
    const size_t rb = (size_t)row*CDIM;
    double x0 = (double)visual[rb+tid], x1 = (double)visual[rb+tid+256];
    double s = blocksumd4(x0+x1, red);
    double mu = s*(1.0/512.0);
    double d0 = x0-mu, d1 = x1-mu;
    double var = blocksumd4(d0*d0+d1*d1, red);
    double rs = 1.0/sqrt(var*(1.0/512.0) + 1e-5);
    vis64[tid]     = d0*rs*(double)g1[tid]     + (double)be1[tid];
    vis64[tid+256] = d1*rs*(double)g1[tid+256] + (double)be1[tid+256];
    __syncthreads();
    double qa0=(double)bq[tid], qa1=(double)bq[tid+256], qa2=(double)bq[tid+512];
#pragma unroll 4
    for (int c=0;c<CDIM;c++){
      double v = vis64[c];
      const float* wrow = &Wq[(size_t)c*TDIM];
      qa0 += v*(double)wrow[tid];
      qa1 += v*(double)wrow[tid+256];
      qa2 += v*(double)wrow[tid+512];
    }
    q64[tid]=qa0; q64[tid+256]=qa1; q64[tid+512]=qa2;
    double nq2 = blocksumd4(qa0*qa0+qa1*qa1+qa2*qa2, red);
    double nq = sqrt(nq2); if (nq < 1e-12) nq = 1e-12;
    __syncthreads();
    if (tid < KKEY){
      const float* trow = &text[((size_t)b*KKEY + tid)*TDIM];
      double dot=0.0, nk2=0.0;
#pragma unroll 8
      for (int j=0;j<TDIM;j++){
        double tv = (double)trow[j];
        dot += q64[j]*tv; nk2 += tv*tv;
      }
      double nk = sqrt(nk2); if (nk < 1e-12) nk = 1e-12;
      sims[tid] = dot/(nq*nk);
    }
    __syncthreads();
    if (w == 0){
      double v0=sims[lane], v1=sims[lane+64];
      bool rm0=false, rm1=false;
      double thr=0.0, smax=0.0;
      for (int it=0; it<5; ++it){
        double c0 = rm0 ? -1e300 : v0;
        double c1 = rm1 ? -1e300 : v1;
        double m = wmaxd(c0>c1 ? c0 : c1);
        if (it==0) smax = m;
        thr = m;
        bool h0 = (!rm0) && (v0==m);
        u64 k0 = __ballot(h0);
        if (k0){ if (lane == __ffsll(k0)-1) rm0 = true; }
        else {
          bool h1 = (!rm1) && (v1==m);
          u64 k1 = __ballot(h1);
          if (lane == __ffsll(k1)-1) rm1 = true;
        }
      }
      if (lane==0){ sc2[0]=smax; sc2[1]=thr; kcount=0; }
    }
    __syncthreads();
    const double smax = sc2[0], thr = sc2[1];
    double p = 0.0;
    if (tid < KKEY){
      double sv = sims[tid];
      p = (sv >= thr) ? exp((sv-smax)*(1.0/0.07)) : 0.0;
      pw[tid] = p;
      if (p > 0.0){ int pos = atomicAdd(&kcount, 1); klist[pos] = tid; }
    }
    double Z = blocksumd4(p, red);
    double zi = 1.0/Z;
    __syncthreads();
    double a0=(double)bv[tid], a1=(double)bv[tid+256];
    int kc = kcount;
    for (int ki=0; ki<kc; ++ki){
      int k = klist[ki];
      double wt = pw[k]*zi;
      const float* vr = &value[((size_t)b*KKEY + k)*CDIM];
      a0 += wt*(double)vr[tid];
      a1 += wt*(double)vr[tid+256];
    }
    double f0 = (double)visual[rb+tid]     + a0;
    double f1 = (double)visual[rb+tid+256] + a1;
    double fsum = blocksumd4(f0+f1, red);
    double fmu = fsum*(1.0/512.0);
    double e0=f0-fmu, e1=f1-fmu;
    double fvar = blocksumd4(e0*e0+e1*e1, red);
    double frs = 1.0/sqrt(fvar*(1.0/512.0) + 1e-5);
    fused16[rb+tid]     = f2h((float)(e0*frs*(double)g2[tid]     + (double)be2[tid]));
    fused16[rb+tid+256] = f2h((float)(e1*frs*(double)g2[tid+256] + (double)be2[tid+256]));
    __syncthreads();
  }
}

// ---------------------------------------------------------------------------
// Attention + residual + LN2: one wave per row, no LDS. Sums 3 t-planes.
// ---------------------------------------------------------------------------
__global__ __launch_bounds__(256) void attn_ln2_kernel(
    const float* __restrict__ visual,
    const float* __restrict__ tbuf, const float* __restrict__ crr,
    const float* __restrict__ normk, const float* __restrict__ qpart,
    const float* __restrict__ value, const float* __restrict__ bv,
    const float* __restrict__ g2, const float* __restrict__ be2,
    u16* __restrict__ fused16,
    int* __restrict__ rcnt, int* __restrict__ rlist)
{
  const int w = threadIdx.x >> 6, lane = threadIdx.x & 63;
  const int row = blockIdx.x*4 + w;
  const int b = row >> 12;
  float nqp = (lane < 12) ? qpart[(size_t)row*12 + lane] : 0.f;
  float nq2 = wsumf(nqp);
  float nq = fmaxf(sqrtf(nq2), 1e-12f);
  const float* t0 = &tbuf[(size_t)row*KKEY];
  const float* t1 = t0 + (size_t)NROWS*KKEY;
  const float* t2 = t1 + (size_t)NROWS*KKEY;
  float ta = t0[lane]    + t1[lane]    + t2[lane];
  float tb = t0[lane+64] + t1[lane+64] + t2[lane+64];
  float s0 = (ta + crr[b*KKEY + lane])    / (nq*normk[b*KKEY + lane]);
  float s1 = (tb + crr[b*KKEY + lane+64]) / (nq*normk[b*KKEY + lane+64]);
  float v0=s0, v1=s1; bool rm0=false, rm1=false;
  float thr=0.f, smax=0.f, m6=0.f;
  for (int it=0; it<6; ++it){
    float c0 = rm0 ? -1e30f : v0;
    float c1 = rm1 ? -1e30f : v1;
    float m = wmaxf(fmaxf(c0,c1));
    if (it==0) smax = m;
    if (it<5){
      thr = m;
      bool h0 = (!rm0) && (v0==m);
      u64 k0 = __ballot(h0);
      if (k0){ if (lane == __ffsll(k0)-1) rm0 = true; }
      else {
        bool h1 = (!rm1) && (v1==m);
        u64 k1 = __ballot(h1);
        if (lane == __ffsll(k1)-1) rm1 = true;
      }
    } else m6 = m;
  }
  if ((thr - m6) < RESCUE_MARGIN){
    if (lane == 0){
      int p = atomicAdd(rcnt, 1);
      rlist[p] = row;
    }
    return;
  }
  float p0 = (s0>=thr) ? expf((s0-smax)*TINV) : 0.f;
  float p1 = (s1>=thr) ? expf((s1-smax)*TINV) : 0.f;
  float Z = wsumf(p0+p1);
  float zi = 1.f/Z;
  float accv[8];
#pragma unroll
  for (int j=0;j<8;j++) accv[j] = bv[lane*8+j];
  u64 mk0 = __ballot(p0>0.f);
  u64 mk1 = __ballot(p1>0.f);
  while (mk0){
    int l = __ffsll(mk0)-1; mk0 &= mk0-1;
    float wt = __shfl(p0, l)*zi;
    const f32x4* vr = (const f32x4*)&value[((size_t)b*KKEY + l)*CDIM + lane*8];
    f32x4 va = vr[0], vb = vr[1];
#pragma unroll
    for (int j=0;j<4;j++){ accv[j] += wt*va[j]; accv[4+j] += wt*vb[j]; }
  }
  while (mk1){
    int l = __ffsll(mk1)-1; mk1 &= mk1-1;
    float wt = __shfl(p1, l)*zi;
    const f32x4* vr = (const f32x4*)&value[((size_t)b*KKEY + l + 64)*CDIM + lane*8];
    f32x4 va = vr[0], vb = vr[1];
#pragma unroll
    for (int j=0;j<4;j++){ accv[j] += wt*va[j]; accv[4+j] += wt*vb[j]; }
  }
  size_t rb = (size_t)row*CDIM + lane*8;
  f32x4 r0v = *(const f32x4*)&visual[rb];
  f32x4 r1v = *(const f32x4*)&visual[rb+4];
  float f[8];
#pragma unroll
  for (int j=0;j<4;j++){ f[j]=r0v[j]+accv[j]; f[4+j]=r1v[j]+accv[4+j]; }
  float fs=0.f;
#pragma unroll
  for (int j=0;j<8;j++) fs += f[j];
  fs = wsumf(fs);
  float fmu = fs*(1.0f/512.0f);
  float fvv=0.f;
#pragma unroll
  for (int j=0;j<8;j++){ float d=f[j]-fmu; fvv+=d*d; }
  fvv = wsumf(fvv);
  float frs = rsqrtf(fvv*(1.0f/512.0f) + LN_EPS_);
  int cb = lane*8;
  f32x4 o0,o1;
#pragma unroll
  for (int j=0;j<4;j++) o0[j] = (f[j]-fmu)*frs*g2[cb+j]     + be2[cb+j];
#pragma unroll
  for (int j=0;j<4;j++) o1[j] = (f[4+j]-fmu)*frs*g2[cb+4+j] + be2[cb+4+j];
  u32x4 hv;
  hv[0]=pk2(o0[0],o0[1]); hv[1]=pk2(o0[2],o0[3]);
  hv[2]=pk2(o1[0],o1[1]); hv[3]=pk2(o1[2],o1[3]);
  *(u32x4*)&fused16[rb] = hv;
}

// ---------------------------------------------------------------------------
extern "C" void kernel_launch(void* const* d_in, const int* in_sizes, int n_in,
                              void* d_out, int out_size, void* d_ws, size_t ws_size,
                              hipStream_t stream)
{
  (void)in_sizes; (void)n_in; (void)out_size; (void)ws_size;
  const float* visual = (const float*)d_in[0];
  const float* text   = (const float*)d_in[1];
  const float* Wq     = (const float*)d_in[2];
  const float* bq     = (const float*)d_in[3];
  const float* Wv     = (const float*)d_in[4];
  const float* bv     = (const float*)d_in[5];
  const float* W1     = (const float*)d_in[6];
  const float* b1     = (const float*)d_in[7];
  const float* W2     = (const float*)d_in[8];
  const float* b2     = (const float*)d_in[9];
  const float* g1     = (const float*)d_in[10];
  const float* be1    = (const float*)d_in[11];
  const float* g2     = (const float*)d_in[12];
  const float* be2    = (const float*)d_in[13];
  float* out = (float*)d_out;

  char* ws = (char*)d_ws;
  size_t off = 0;
  auto alloc = [&](size_t bytes)->char*{
    char* p = ws + off; off += (bytes + 255) & ~(size_t)255; return p; };

  u16*    visH   = (u16*)   alloc((size_t)NROWS*CDIM*2);
  u16*    visL   = (u16*)   alloc((size_t)NROWS*CDIM*2);
  u16*    h16    = (u16*)   alloc((size_t)NROWS*FFDIM*2);
  u16*    fused16= (u16*)   alloc((size_t)NROWS*CDIM*2);
  u16*    MrtH   = (u16*)   alloc((size_t)NB*KKEY*CDIM*2);
  u16*    MrtL   = (u16*)   alloc((size_t)NB*KKEY*CDIM*2);
  float*  value  = (float*) alloc((size_t)NB*KKEY*CDIM*4);
  u16*    Wqbt   = (u16*)   alloc((size_t)TDIM*CDIM*2);
  u16*    W116t  = (u16*)   alloc((size_t)FFDIM*CDIM*2);
  u16*    W216t  = (u16*)   alloc((size_t)CDIM*FFDIM*2);
  float*  WvT    = (float*) alloc((size_t)CDIM*TDIM*4);
  float*  qpart  = (float*) alloc((size_t)NROWS*12*4);
  float*  normk  = (float*) alloc((size_t)NB*KKEY*4);
  float*  crr    = (float*) alloc((size_t)NB*KKEY*4);
  int*    rcnt   = (int*)   alloc(256);
  int*    rlist  = (int*)   alloc((size_t)NROWS*4);
  // tbuf (3 planes, 48 MB) aliases h16 (128 MB): gemm_t writes + attn reads
  // complete (stream-ordered) before FFN1 overwrites h16 each iteration.
  float*  tbuf   = (float*)h16;

  hipMemsetAsync(rcnt, 0, sizeof(int), stream);

  transpose_all_kernel<<<2816, dim3(32,8), 0, stream>>>(
      Wq, W1, W2, Wv, Wqbt, W116t, W216t, WvT);
  keystats_kernel<<<256, 256, 0, stream>>>(text, bq, normk, crr);
  gemm_txt_kernel<<<dim3(2, 8, 16), 256, 0, stream>>>(
      text, Wq, WvT, MrtH, MrtL, value);
  ln1_kernel<<<NROWS/4, 256, 0, stream>>>(visual, g1, be1, visH, visL);
  gemm_t_kernel<<<dim3(256, 3), 256, 0, stream>>>(visH, visL, MrtH, MrtL, tbuf);
  gemm_f16_kernel<0,TDIM,CDIM,6><<<1536, 256, 0, stream>>>(
      visH, Wqbt, bq, qpart, nullptr, nullptr);
  attn_ln2_kernel<<<NROWS/4, 256, 0, stream>>>(
      visual, tbuf, crr, normk, qpart, value, bv, g2, be2,
      fused16, rcnt, rlist);
  rescue_kernel<<<256, 256, 0, stream>>>(
      rcnt, rlist, visual, text, Wq, bq, g1, be1, g2, be2, value, bv, fused16);
  gemm_f16_kernel<1,FFDIM,CDIM,16><<<4096, 256, 0, stream>>>(
      fused16, W116t, b1, nullptr, h16, nullptr);
  gemm_f16_kernel<2,CDIM,FFDIM,4><<<1024, 256, 0, stream>>>(
      h16, W216t, b2, out, nullptr, fused16);
}